// Round 17
// baseline (1903.424 us; speedup 1.0000x reference)
//
#include <hip/hip_runtime.h>

#define BG 8
#define NP 4096
#define MC 2048
#define KN 64
#define NWK 248
#define CAND 480

// Exact-rounding squared distance matching JAX/np f32 semantics.
__device__ __forceinline__ float dist2(float ax, float ay, float az,
                                       float bx, float by, float bz) {
    float dx = __fsub_rn(ax, bx), dy = __fsub_rn(ay, by), dz = __fsub_rn(az, bz);
    return __fadd_rn(__fadd_rn(__fmul_rn(dx, dx), __fmul_rn(dy, dy)), __fmul_rn(dz, dz));
}

template <int CTRL>
__device__ __forceinline__ float dppmax(float v) {
    int t = __builtin_amdgcn_update_dpp(0, __float_as_int(v), CTRL, 0xf, 0xf, true);
    return fmaxf(v, __int_as_float(t));
}

// ---- Fused kernel: FPS producers (blocks 0..3, TWO graphs each with independent
// wave-group spin barriers) + y-precompute/kNN/MLP consumers (blocks 4..251) ----
// 98.5 KB static LDS forces exactly 1 block per CU.
__global__ __launch_bounds__(512, 1) void k_fused(
    const float* __restrict__ pos, const float* __restrict__ x,
    const float* __restrict__ w1, const float* __restrict__ b1,
    const float* __restrict__ w2, const float* __restrict__ b2,
    const float* __restrict__ w3, const float* __restrict__ b3,
    float* __restrict__ y,
    float* __restrict__ out_pos, float* __restrict__ out_batch, float* __restrict__ out_x,
    int* __restrict__ prog, int* __restrict__ yready)
{
    __shared__ float smem[24640];   // 98560 B
    const int tid = threadIdx.x;
    if (blockIdx.x < 4) {
        // ======== FPS producer: waves 0-3 -> graph 2*blk, waves 4-7 -> graph 2*blk+1 ========
        const int blk = blockIdx.x;
        const int lane = tid & 63, wv = tid >> 6;
        const int g = wv >> 2, wq = wv & 3;          // group, wave-in-group
        const int b = blk * 2 + g;
        float* posL = smem + g * 12288;
        int* bar = (int*)(smem + 24576) + g * 16;    // per-group arrival counter (64B apart)
        float2* sl = (float2*)(smem + 24608) + g * 8;   // per-group [2][4] (V, idx) dbuf slots
        {
            const float* src = pos + (size_t)blk * 2 * NP * 3;
            for (int i = tid; i < 2 * NP * 3; i += 512) smem[i] = src[i];
        }
        if (tid < 32) ((int*)(smem + 24576))[tid] = 0;
        __syncthreads();    // once; no block barriers after this point
        const int tgrp = wq * 64 + lane;             // 0..255 within group
        float px[16], py[16], pz[16], mind[16];
        const int base = tgrp * 16;
        #pragma unroll
        for (int i = 0; i < 16; i++) {
            px[i] = posL[(base + i) * 3];
            py[i] = posL[(base + i) * 3 + 1];
            pz[i] = posL[(base + i) * 3 + 2];
            mind[i] = 1e30f;
        }
        float cx = posL[0], cy = posL[1], cz = posL[2];
        if (tgrp == 0) {
            const size_t c3 = (size_t)b * MC * 3;
            __hip_atomic_store(&out_pos[c3 + 0], cx, __ATOMIC_RELAXED, __HIP_MEMORY_SCOPE_AGENT);
            __hip_atomic_store(&out_pos[c3 + 1], cy, __ATOMIC_RELAXED, __HIP_MEMORY_SCOPE_AGENT);
            __hip_atomic_store(&out_pos[c3 + 2], cz, __ATOMIC_RELAXED, __HIP_MEMORY_SCOPE_AGENT);
        }
        for (int m = 1; m < MC; m++) {
            // update min distances; track thread-local (max, first idx)
            float bv = -1.0f; int bi = base;
            #pragma unroll
            for (int i = 0; i < 16; i++) {
                float d = dist2(px[i], py[i], pz[i], cx, cy, cz);
                float nm = fminf(mind[i], d);
                mind[i] = nm;
                if (nm > bv) { bv = nm; bi = base + i; }  // strict > keeps first idx
            }
            // wave max via DPP
            float v = bv;
            v = dppmax<0x111>(v);  // row_shr:1
            v = dppmax<0x112>(v);  // row_shr:2
            v = dppmax<0x114>(v);  // row_shr:4
            v = dppmax<0x118>(v);  // row_shr:8
            v = dppmax<0x142>(v);  // row_bcast:15
            v = dppmax<0x143>(v);  // row_bcast:31
            const float V = __int_as_float(__builtin_amdgcn_readlane(__float_as_int(v), 63));
            unsigned long long mk = __ballot(bv == V);
            float2* sb = sl + (m & 1) * 4;
            if (lane == (int)(__ffsll((long long)mk) - 1))
                sb[wq] = make_float2(V, __int_as_float(bi));
            // ---- group spin barrier (generation = 4*m arrivals) ----
            if (lane == 0)
                __hip_atomic_fetch_add(bar, 1, __ATOMIC_RELEASE, __HIP_MEMORY_SCOPE_WORKGROUP);
            const int target = 4 * m;
            while (__hip_atomic_load(bar, __ATOMIC_ACQUIRE, __HIP_MEMORY_SCOPE_WORKGROUP) < target)
                __builtin_amdgcn_s_sleep(1);
            // ---- fold 4 slots (ascending wave, strict > => first-index semantics) ----
            const float4* sq = (const float4*)sb;
            float4 q0 = sq[0], q1 = sq[1];
            float Vg = q0.x; int ig = __float_as_int(q0.y);
            if (q0.z > Vg) { Vg = q0.z; ig = __float_as_int(q0.w); }
            if (q1.x > Vg) { Vg = q1.x; ig = __float_as_int(q1.y); }
            if (q1.z > Vg) { Vg = q1.z; ig = __float_as_int(q1.w); }
            cx = posL[ig * 3]; cy = posL[ig * 3 + 1]; cz = posL[ig * 3 + 2];
            if (tgrp == 0) {
                // drain center-(m-1) stores (issued one full iteration ago -> ~free),
                // then publish center m and prog=m (centers 0..m-1 guaranteed visible)
                asm volatile("s_waitcnt vmcnt(0)" ::: "memory");
                const size_t c3 = (size_t)(b * MC + m) * 3;
                __hip_atomic_store(&out_pos[c3 + 0], cx, __ATOMIC_RELAXED, __HIP_MEMORY_SCOPE_AGENT);
                __hip_atomic_store(&out_pos[c3 + 1], cy, __ATOMIC_RELAXED, __HIP_MEMORY_SCOPE_AGENT);
                __hip_atomic_store(&out_pos[c3 + 2], cz, __ATOMIC_RELAXED, __HIP_MEMORY_SCOPE_AGENT);
                __hip_atomic_store(&prog[b * 16], m, __ATOMIC_RELAXED, __HIP_MEMORY_SCOPE_AGENT);
            }
        }
        if (tgrp == 0) {
            asm volatile("s_waitcnt vmcnt(0)" ::: "memory");
            __hip_atomic_store(&prog[b * 16], MC, __ATOMIC_RELEASE, __HIP_MEMORY_SCOPE_AGENT);
        }
        for (int i = tgrp; i < MC; i += 256) out_batch[b * MC + i] = (float)b;
    } else {
        // ======== Consumer block (R12 logic; blocks 4..251) ========
        const int w = blockIdx.x - 4;         // 0..247
        const int g = w & 7;                  // graph
        const int sub = w >> 3;               // 0..30
        const int lane = tid & 63, ww = tid >> 6;
        const int waveid = sub * 8 + ww;      // 0..247 within graph
        // ---- phase 1: y = x @ W1x + b1 for this block's chunk of graph g ----
        float* wsm = smem;                    // [0, 4096): W1 x-part
        for (int i = tid; i < 4096; i += 512) wsm[i] = w1[i];
        const float b1v = b1[lane];
        __syncthreads();
        const int p0 = sub * 133;
        const int p1 = (p0 + 133 < NP) ? p0 + 133 : NP;
        const float* xg = x + (size_t)g * NP * 64;
        float* yg_w = y + (size_t)g * NP * 64;
        for (int p = p0 + ww; p < p1; p += 8) {
            float xrow = xg[(size_t)p * 64 + lane];
            float acc = b1v;
            #pragma unroll
            for (int f = 0; f < 64; f++) {
                float xf = __shfl(xrow, f, 64);
                acc = fmaf(xf, wsm[f * 64 + lane], acc);
            }
            yg_w[(size_t)p * 64 + lane] = acc;
        }
        __syncthreads();                      // drain this block's y stores
        if (tid == 0)
            __hip_atomic_fetch_add(&yready[g * 16], 1, __ATOMIC_RELEASE, __HIP_MEMORY_SCOPE_AGENT);
        // ---- phase 2: preload weights into registers (overlaps the wait) ----
        float w2c[64], w3a[64], w3b[64];
        #pragma unroll
        for (int f = 0; f < 64; f++) {
            w2c[f] = w2[f * 64 + lane];
            w3a[f] = w3[f * 128 + lane];
            w3b[f] = w3[f * 128 + 64 + lane];
        }
        const float b2v = b2[lane], b3av = b3[lane], b3bv = b3[lane + 64];
        const float wp0 = w1[64 * 64 + lane], wp1 = w1[65 * 64 + lane], wp2 = w1[66 * 64 + lane];
        while (__hip_atomic_load(&yready[g * 16], __ATOMIC_RELAXED, __HIP_MEMORY_SCOPE_AGENT) < 31)
            __builtin_amdgcn_s_sleep(16);
        {
            int yr = __hip_atomic_load(&yready[g * 16], __ATOMIC_ACQUIRE, __HIP_MEMORY_SCOPE_AGENT);
            asm volatile("" :: "v"(yr));      // keep the acquire load alive
        }
        float2* cand = (float2*)(smem + 4096) + ww * CAND;   // floats [4096, 11776)
        int* nlist = (int*)(smem + 11776) + ww * 64;         // floats [11776, 12288)
        float* st1 = smem + 12288 + ww * 136;                // floats [12288, 13376)
        float* st2 = st1 + 68;
        const float* pg = pos + (size_t)g * NP * 3;
        const float* yg = y + (size_t)g * NP * 64;
        for (int m = waveid; m < MC; m += NWK) {
            int cur;
            while ((cur = __hip_atomic_load(&prog[g * 16], __ATOMIC_RELAXED, __HIP_MEMORY_SCOPE_AGENT)) <= m) {
                if (m - cur > 16) __builtin_amdgcn_s_sleep(64);
                else              __builtin_amdgcn_s_sleep(8);
            }
            const int ci = g * MC + m;
            const size_t c3 = (size_t)ci * 3;
            const float cx = __hip_atomic_load(&out_pos[c3 + 0], __ATOMIC_RELAXED, __HIP_MEMORY_SCOPE_AGENT);
            const float cy = __hip_atomic_load(&out_pos[c3 + 1], __ATOMIC_RELAXED, __HIP_MEMORY_SCOPE_AGENT);
            const float cz = __hip_atomic_load(&out_pos[c3 + 2], __ATOMIC_RELAXED, __HIP_MEMORY_SCOPE_AGENT);
            int cnt = 0;
            for (int c = 0; c < 64; c++) {
                const int p = c * 64 + lane;
                float ppx = pg[p * 3], ppy = pg[p * 3 + 1], ppz = pg[p * 3 + 2];
                float d2 = dist2(ppx, ppy, ppz, cx, cy, cz);
                bool inr = d2 <= 0.25f;
                unsigned long long mk = __ballot(inr);
                int pre = __popcll(mk & ((1ull << lane) - 1ull));
                int wp = cnt + pre;
                if (inr && wp < CAND) cand[wp] = make_float2(d2, __int_as_float(p));
                cnt += __popcll(mk);
            }
            if (cnt > CAND) cnt = CAND;
            int kc;
            if (cnt <= KN) {
                kc = cnt;
                if (lane < cnt) nlist[lane] = __float_as_int(cand[lane].y);
            } else {
                kc = KN;
                for (int basej = 0; basej < cnt; basej += 64) {
                    int jj = basej + lane;
                    float dj = 3.4e38f; int ij = 0x7fffffff;
                    bool act = jj < cnt;
                    if (act) { float2 e = cand[jj]; dj = e.x; ij = __float_as_int(e.y); }
                    int rank = 0;
                    for (int l = 0; l < cnt; l++) {
                        float2 e = cand[l];
                        float dl = e.x; int il = __float_as_int(e.y);
                        if (dl < dj || (dl == dj && il < ij)) rank++;
                    }
                    if (act && rank < KN) nlist[rank] = ij;
                }
            }
            float mA = -3.4e38f, mB = -3.4e38f;
            for (int k = 0; k < kc; k++) {
                const int j = nlist[k];
                const float yv = yg[(size_t)j * 64 + lane];
                const float jx = pg[j * 3], jy = pg[j * 3 + 1], jz = pg[j * 3 + 2];
                float rx = jx - cx, ry = jy - cy, rz = jz - cz;
                float h1 = fmaf(rx, wp0, yv);
                h1 = fmaf(ry, wp1, h1);
                h1 = fmaf(rz, wp2, h1);
                h1 = fmaxf(h1, 0.f);
                st1[lane] = h1;
                float a2a = b2v, a2b = 0.f;
                #pragma unroll
                for (int fc = 0; fc < 16; fc += 2) {
                    float4 hA = *(const float4*)&st1[fc * 4];
                    float4 hB = *(const float4*)&st1[fc * 4 + 4];
                    a2a = fmaf(hA.x, w2c[fc * 4], a2a);
                    a2a = fmaf(hA.y, w2c[fc * 4 + 1], a2a);
                    a2a = fmaf(hA.z, w2c[fc * 4 + 2], a2a);
                    a2a = fmaf(hA.w, w2c[fc * 4 + 3], a2a);
                    a2b = fmaf(hB.x, w2c[fc * 4 + 4], a2b);
                    a2b = fmaf(hB.y, w2c[fc * 4 + 5], a2b);
                    a2b = fmaf(hB.z, w2c[fc * 4 + 6], a2b);
                    a2b = fmaf(hB.w, w2c[fc * 4 + 7], a2b);
                }
                float h2 = fmaxf(a2a + a2b, 0.f);
                st2[lane] = h2;
                float a3 = b3av, a4 = b3bv;
                #pragma unroll
                for (int fc = 0; fc < 16; fc++) {
                    float4 h = *(const float4*)&st2[fc * 4];
                    a3 = fmaf(h.x, w3a[fc * 4], a3);
                    a3 = fmaf(h.y, w3a[fc * 4 + 1], a3);
                    a3 = fmaf(h.z, w3a[fc * 4 + 2], a3);
                    a3 = fmaf(h.w, w3a[fc * 4 + 3], a3);
                    a4 = fmaf(h.x, w3b[fc * 4], a4);
                    a4 = fmaf(h.y, w3b[fc * 4 + 1], a4);
                    a4 = fmaf(h.z, w3b[fc * 4 + 2], a4);
                    a4 = fmaf(h.w, w3b[fc * 4 + 3], a4);
                }
                mA = fmaxf(mA, a3);
                mB = fmaxf(mB, a4);
            }
            out_x[(size_t)ci * 128 + lane] = mA;
            out_x[(size_t)ci * 128 + 64 + lane] = mB;
        }
    }
}

extern "C" void kernel_launch(void* const* d_in, const int* in_sizes, int n_in,
                              void* d_out, int out_size, void* d_ws, size_t ws_size,
                              hipStream_t stream) {
    const float* x   = (const float*)d_in[0];
    const float* pos = (const float*)d_in[1];
    const float* w1  = (const float*)d_in[3];
    const float* b1  = (const float*)d_in[4];
    const float* w2  = (const float*)d_in[5];
    const float* b2  = (const float*)d_in[6];
    const float* w3  = (const float*)d_in[7];
    const float* b3  = (const float*)d_in[8];

    float* out_x     = (float*)d_out;                       // [B*M,128]
    float* out_pos   = out_x + (size_t)BG * MC * 128;       // [B*M,3]
    float* out_batch = out_pos + (size_t)BG * MC * 3;       // [B*M] (written as float)

    char* ws    = (char*)d_ws;
    float* y    = (float*)ws;                   // 8 MB: [B*N,64] = x@W1x + b1
    int* prog   = (int*)(ws + 8388608);         // 8 x 16 ints (64B stride per graph)
    int* yready = (int*)(ws + 8389120);         // 8 x 16 ints

    (void)hipMemsetAsync(prog, 0, 1024, stream);  // prog + yready
    hipLaunchKernelGGL(k_fused, dim3(252), dim3(512), 0, stream,
                       pos, x, w1, b1, w2, b2, w3, b3,
                       y, out_pos, out_batch, out_x, prog, yready);
}

// Round 18
// 1428.335 us; speedup vs baseline: 1.3326x; 1.3326x over previous
//
#include <hip/hip_runtime.h>

#define BG 8
#define NP 4096
#define MC 2048
#define KN 64
#define NWK 248
#define CAND 480

// Exact-rounding squared distance matching JAX/np f32 semantics.
__device__ __forceinline__ float dist2(float ax, float ay, float az,
                                       float bx, float by, float bz) {
    float dx = __fsub_rn(ax, bx), dy = __fsub_rn(ay, by), dz = __fsub_rn(az, bz);
    return __fadd_rn(__fadd_rn(__fmul_rn(dx, dx), __fmul_rn(dy, dy)), __fmul_rn(dz, dz));
}

template <int CTRL>
__device__ __forceinline__ float dppmax(float v) {
    int t = __builtin_amdgcn_update_dpp(0, __float_as_int(v), CTRL, 0xf, 0xf, true);
    return fmaxf(v, __int_as_float(t));
}

// Barrier that drains ONLY LDS (lgkmcnt) — global stores keep flying.
__device__ __forceinline__ void barrier_lds_only() {
    asm volatile("s_waitcnt lgkmcnt(0)" ::: "memory");
    __builtin_amdgcn_s_barrier();
}

// ---- Fused kernel: FPS producers (blocks 0..7) + y-precompute/kNN/MLP consumers (8..255) ----
// 96 KB static LDS forces exactly 1 block per CU.
__global__ __launch_bounds__(512, 1) void k_fused(
    const float* __restrict__ pos, const float* __restrict__ x,
    const float* __restrict__ w1, const float* __restrict__ b1,
    const float* __restrict__ w2, const float* __restrict__ b2,
    const float* __restrict__ w3, const float* __restrict__ b3,
    float* __restrict__ y,
    float* __restrict__ out_pos, float* __restrict__ out_batch, float* __restrict__ out_x,
    int* __restrict__ prog, int* __restrict__ yready)
{
    __shared__ float smem[24576];   // 96 KB
    const int tid = threadIdx.x;
    if (blockIdx.x < BG) {
        // ======== FPS producer (R3-exact structure, 8 waves x 8 pts/thread) ========
        const int b = blockIdx.x;
        const float* pg = pos + (size_t)b * NP * 3;
        for (int i = tid; i < NP * 3; i += 512) smem[i] = pg[i];
        __syncthreads();
        const int lane = tid & 63, wv = tid >> 6;
        float px[8], py[8], pz[8], mind[8];
        const int base = tid * 8;
        #pragma unroll
        for (int i = 0; i < 8; i++) {
            px[i] = smem[(base + i) * 3];
            py[i] = smem[(base + i) * 3 + 1];
            pz[i] = smem[(base + i) * 3 + 2];
            mind[i] = 1e30f;
        }
        float2* sl = (float2*)(smem + NP * 3);   // 2 x 8 double-buffered (V, idx) slots
        float cx = smem[0], cy = smem[1], cz = smem[2];
        if (tid == 0) {
            const size_t c3 = (size_t)b * MC * 3;
            __hip_atomic_store(&out_pos[c3 + 0], cx, __ATOMIC_RELAXED, __HIP_MEMORY_SCOPE_AGENT);
            __hip_atomic_store(&out_pos[c3 + 1], cy, __ATOMIC_RELAXED, __HIP_MEMORY_SCOPE_AGENT);
            __hip_atomic_store(&out_pos[c3 + 2], cz, __ATOMIC_RELAXED, __HIP_MEMORY_SCOPE_AGENT);
        }
        for (int m = 1; m < MC; m++) {
            float bv = -1.0f; int bi = base;
            #pragma unroll
            for (int i = 0; i < 8; i++) {
                float d = dist2(px[i], py[i], pz[i], cx, cy, cz);
                float nm = fminf(mind[i], d);
                mind[i] = nm;
                if (nm > bv) { bv = nm; bi = base + i; }  // strict > keeps first idx
            }
            float v = bv;
            v = dppmax<0x111>(v);  // row_shr:1
            v = dppmax<0x112>(v);  // row_shr:2
            v = dppmax<0x114>(v);  // row_shr:4
            v = dppmax<0x118>(v);  // row_shr:8
            v = dppmax<0x142>(v);  // row_bcast:15
            v = dppmax<0x143>(v);  // row_bcast:31
            const float V = __int_as_float(__builtin_amdgcn_readlane(__float_as_int(v), 63));
            unsigned long long mk = __ballot(bv == V);
            float2* sb = sl + (m & 1) * 8;
            if (lane == (int)(__ffsll((long long)mk) - 1))
                sb[wv] = make_float2(V, __int_as_float(bi));
            // LDS-only barrier: does NOT wait for tid0's in-flight global stores
            barrier_lds_only();
            const float4* sq = (const float4*)sb;
            float4 q0 = sq[0], q1 = sq[1], q2 = sq[2], q3 = sq[3];
            float Vg = q0.x; int ig = __float_as_int(q0.y);
            if (q0.z > Vg) { Vg = q0.z; ig = __float_as_int(q0.w); }
            if (q1.x > Vg) { Vg = q1.x; ig = __float_as_int(q1.y); }
            if (q1.z > Vg) { Vg = q1.z; ig = __float_as_int(q1.w); }
            if (q2.x > Vg) { Vg = q2.x; ig = __float_as_int(q2.y); }
            if (q2.z > Vg) { Vg = q2.z; ig = __float_as_int(q2.w); }
            if (q3.x > Vg) { Vg = q3.x; ig = __float_as_int(q3.y); }
            if (q3.z > Vg) { Vg = q3.z; ig = __float_as_int(q3.w); }
            cx = smem[ig * 3]; cy = smem[ig * 3 + 1]; cz = smem[ig * 3 + 2];
            if (tid == 0) {
                // Drain center-(m-1) stores (issued a full iteration ago -> ~free),
                // THEN publish center m and prog=m: consumers seeing prog>=m have
                // centers 0..m-1 guaranteed visible (lag-by-one protocol).
                asm volatile("s_waitcnt vmcnt(0)" ::: "memory");
                const size_t c3 = (size_t)(b * MC + m) * 3;
                __hip_atomic_store(&out_pos[c3 + 0], cx, __ATOMIC_RELAXED, __HIP_MEMORY_SCOPE_AGENT);
                __hip_atomic_store(&out_pos[c3 + 1], cy, __ATOMIC_RELAXED, __HIP_MEMORY_SCOPE_AGENT);
                __hip_atomic_store(&out_pos[c3 + 2], cz, __ATOMIC_RELAXED, __HIP_MEMORY_SCOPE_AGENT);
                __hip_atomic_store(&prog[b * 16], m, __ATOMIC_RELAXED, __HIP_MEMORY_SCOPE_AGENT);
            }
        }
        if (tid == 0) {
            asm volatile("s_waitcnt vmcnt(0)" ::: "memory");   // drain final center
            __hip_atomic_store(&prog[b * 16], MC, __ATOMIC_RELEASE, __HIP_MEMORY_SCOPE_AGENT);
        }
        for (int i = tid; i < MC; i += 512) out_batch[b * MC + i] = (float)b;
    } else {
        // ======== Consumer block (identical to R16) ========
        const int w = blockIdx.x - BG;        // 0..247
        const int g = w & 7;                  // graph
        const int sub = w >> 3;               // 0..30
        const int lane = tid & 63, ww = tid >> 6;
        const int waveid = sub * 8 + ww;      // 0..247 within graph
        // ---- phase 1: y = x @ W1x + b1 for this block's chunk of graph g ----
        float* wsm = smem;                    // [0, 4096): W1 x-part
        for (int i = tid; i < 4096; i += 512) wsm[i] = w1[i];
        const float b1v = b1[lane];
        __syncthreads();
        const int p0 = sub * 133;
        const int p1 = (p0 + 133 < NP) ? p0 + 133 : NP;
        const float* xg = x + (size_t)g * NP * 64;
        float* yg_w = y + (size_t)g * NP * 64;
        for (int p = p0 + ww; p < p1; p += 8) {
            float xrow = xg[(size_t)p * 64 + lane];
            float acc = b1v;
            #pragma unroll
            for (int f = 0; f < 64; f++) {
                float xf = __shfl(xrow, f, 64);
                acc = fmaf(xf, wsm[f * 64 + lane], acc);
            }
            yg_w[(size_t)p * 64 + lane] = acc;
        }
        __syncthreads();                      // drain this block's y stores
        if (tid == 0)
            __hip_atomic_fetch_add(&yready[g * 16], 1, __ATOMIC_RELEASE, __HIP_MEMORY_SCOPE_AGENT);
        // ---- phase 2: preload weights into registers (overlaps the wait) ----
        float w2c[64], w3a[64], w3b[64];
        #pragma unroll
        for (int f = 0; f < 64; f++) {
            w2c[f] = w2[f * 64 + lane];
            w3a[f] = w3[f * 128 + lane];
            w3b[f] = w3[f * 128 + 64 + lane];
        }
        const float b2v = b2[lane], b3av = b3[lane], b3bv = b3[lane + 64];
        const float wp0 = w1[64 * 64 + lane], wp1 = w1[65 * 64 + lane], wp2 = w1[66 * 64 + lane];
        while (__hip_atomic_load(&yready[g * 16], __ATOMIC_RELAXED, __HIP_MEMORY_SCOPE_AGENT) < 31)
            __builtin_amdgcn_s_sleep(16);
        {
            int yr = __hip_atomic_load(&yready[g * 16], __ATOMIC_ACQUIRE, __HIP_MEMORY_SCOPE_AGENT);
            asm volatile("" :: "v"(yr));      // keep the acquire load alive
        }
        float2* cand = (float2*)(smem + 4096) + ww * CAND;   // floats [4096, 11776)
        int* nlist = (int*)(smem + 11776) + ww * 64;         // floats [11776, 12288)
        float* st1 = smem + 12288 + ww * 136;                // floats [12288, 13376)
        float* st2 = st1 + 68;
        const float* pg = pos + (size_t)g * NP * 3;
        const float* yg = y + (size_t)g * NP * 64;
        for (int m = waveid; m < MC; m += NWK) {
            int cur;
            while ((cur = __hip_atomic_load(&prog[g * 16], __ATOMIC_RELAXED, __HIP_MEMORY_SCOPE_AGENT)) <= m) {
                if (m - cur > 16) __builtin_amdgcn_s_sleep(64);
                else              __builtin_amdgcn_s_sleep(8);
            }
            const int ci = g * MC + m;
            const size_t c3 = (size_t)ci * 3;
            const float cx = __hip_atomic_load(&out_pos[c3 + 0], __ATOMIC_RELAXED, __HIP_MEMORY_SCOPE_AGENT);
            const float cy = __hip_atomic_load(&out_pos[c3 + 1], __ATOMIC_RELAXED, __HIP_MEMORY_SCOPE_AGENT);
            const float cz = __hip_atomic_load(&out_pos[c3 + 2], __ATOMIC_RELAXED, __HIP_MEMORY_SCOPE_AGENT);
            int cnt = 0;
            for (int c = 0; c < 64; c++) {
                const int p = c * 64 + lane;
                float ppx = pg[p * 3], ppy = pg[p * 3 + 1], ppz = pg[p * 3 + 2];
                float d2 = dist2(ppx, ppy, ppz, cx, cy, cz);
                bool inr = d2 <= 0.25f;
                unsigned long long mk = __ballot(inr);
                int pre = __popcll(mk & ((1ull << lane) - 1ull));
                int wp = cnt + pre;
                if (inr && wp < CAND) cand[wp] = make_float2(d2, __int_as_float(p));
                cnt += __popcll(mk);
            }
            if (cnt > CAND) cnt = CAND;
            int kc;
            if (cnt <= KN) {
                kc = cnt;
                if (lane < cnt) nlist[lane] = __float_as_int(cand[lane].y);
            } else {
                kc = KN;
                for (int basej = 0; basej < cnt; basej += 64) {
                    int jj = basej + lane;
                    float dj = 3.4e38f; int ij = 0x7fffffff;
                    bool act = jj < cnt;
                    if (act) { float2 e = cand[jj]; dj = e.x; ij = __float_as_int(e.y); }
                    int rank = 0;
                    for (int l = 0; l < cnt; l++) {
                        float2 e = cand[l];
                        float dl = e.x; int il = __float_as_int(e.y);
                        if (dl < dj || (dl == dj && il < ij)) rank++;
                    }
                    if (act && rank < KN) nlist[rank] = ij;
                }
            }
            float mA = -3.4e38f, mB = -3.4e38f;
            for (int k = 0; k < kc; k++) {
                const int j = nlist[k];
                const float yv = yg[(size_t)j * 64 + lane];
                const float jx = pg[j * 3], jy = pg[j * 3 + 1], jz = pg[j * 3 + 2];
                float rx = jx - cx, ry = jy - cy, rz = jz - cz;
                float h1 = fmaf(rx, wp0, yv);
                h1 = fmaf(ry, wp1, h1);
                h1 = fmaf(rz, wp2, h1);
                h1 = fmaxf(h1, 0.f);
                st1[lane] = h1;
                float a2a = b2v, a2b = 0.f;
                #pragma unroll
                for (int fc = 0; fc < 16; fc += 2) {
                    float4 hA = *(const float4*)&st1[fc * 4];
                    float4 hB = *(const float4*)&st1[fc * 4 + 4];
                    a2a = fmaf(hA.x, w2c[fc * 4], a2a);
                    a2a = fmaf(hA.y, w2c[fc * 4 + 1], a2a);
                    a2a = fmaf(hA.z, w2c[fc * 4 + 2], a2a);
                    a2a = fmaf(hA.w, w2c[fc * 4 + 3], a2a);
                    a2b = fmaf(hB.x, w2c[fc * 4 + 4], a2b);
                    a2b = fmaf(hB.y, w2c[fc * 4 + 5], a2b);
                    a2b = fmaf(hB.z, w2c[fc * 4 + 6], a2b);
                    a2b = fmaf(hB.w, w2c[fc * 4 + 7], a2b);
                }
                float h2 = fmaxf(a2a + a2b, 0.f);
                st2[lane] = h2;
                float a3 = b3av, a4 = b3bv;
                #pragma unroll
                for (int fc = 0; fc < 16; fc++) {
                    float4 h = *(const float4*)&st2[fc * 4];
                    a3 = fmaf(h.x, w3a[fc * 4], a3);
                    a3 = fmaf(h.y, w3a[fc * 4 + 1], a3);
                    a3 = fmaf(h.z, w3a[fc * 4 + 2], a3);
                    a3 = fmaf(h.w, w3a[fc * 4 + 3], a3);
                    a4 = fmaf(h.x, w3b[fc * 4], a4);
                    a4 = fmaf(h.y, w3b[fc * 4 + 1], a4);
                    a4 = fmaf(h.z, w3b[fc * 4 + 2], a4);
                    a4 = fmaf(h.w, w3b[fc * 4 + 3], a4);
                }
                mA = fmaxf(mA, a3);
                mB = fmaxf(mB, a4);
            }
            out_x[(size_t)ci * 128 + lane] = mA;
            out_x[(size_t)ci * 128 + 64 + lane] = mB;
        }
    }
}

extern "C" void kernel_launch(void* const* d_in, const int* in_sizes, int n_in,
                              void* d_out, int out_size, void* d_ws, size_t ws_size,
                              hipStream_t stream) {
    const float* x   = (const float*)d_in[0];
    const float* pos = (const float*)d_in[1];
    const float* w1  = (const float*)d_in[3];
    const float* b1  = (const float*)d_in[4];
    const float* w2  = (const float*)d_in[5];
    const float* b2  = (const float*)d_in[6];
    const float* w3  = (const float*)d_in[7];
    const float* b3  = (const float*)d_in[8];

    float* out_x     = (float*)d_out;                       // [B*M,128]
    float* out_pos   = out_x + (size_t)BG * MC * 128;       // [B*M,3]
    float* out_batch = out_pos + (size_t)BG * MC * 3;       // [B*M] (written as float)

    char* ws    = (char*)d_ws;
    float* y    = (float*)ws;                   // 8 MB: [B*N,64] = x@W1x + b1
    int* prog   = (int*)(ws + 8388608);         // 8 x 16 ints (64B stride per graph)
    int* yready = (int*)(ws + 8389120);         // 8 x 16 ints

    (void)hipMemsetAsync(prog, 0, 1024, stream);  // prog + yready
    hipLaunchKernelGGL(k_fused, dim3(256), dim3(512), 0, stream,
                       pos, x, w1, b1, w2, b2, w3, b3,
                       y, out_pos, out_batch, out_x, prog, yready);
}

// Round 19
// 1363.034 us; speedup vs baseline: 1.3965x; 1.0479x over previous
//
#include <hip/hip_runtime.h>

#define BG 8
#define NP 4096
#define MC 2048
#define KN 64
#define NWK 248
#define CAND 480

// Exact-rounding squared distance matching JAX/np f32 semantics.
__device__ __forceinline__ float dist2(float ax, float ay, float az,
                                       float bx, float by, float bz) {
    float dx = __fsub_rn(ax, bx), dy = __fsub_rn(ay, by), dz = __fsub_rn(az, bz);
    return __fadd_rn(__fadd_rn(__fmul_rn(dx, dx), __fmul_rn(dy, dy)), __fmul_rn(dz, dz));
}

template <int CTRL>
__device__ __forceinline__ float dppmax(float v) {
    int t = __builtin_amdgcn_update_dpp(0, __float_as_int(v), CTRL, 0xf, 0xf, true);
    return fmaxf(v, __int_as_float(t));
}

// ---- Fused kernel: FPS producers (blocks 0..7) + y-precompute/kNN/MLP consumers (8..255) ----
// 96 KB static LDS forces exactly 1 block per CU.
__global__ __launch_bounds__(512, 1) void k_fused(
    const float* __restrict__ pos, const float* __restrict__ x,
    const float* __restrict__ w1, const float* __restrict__ b1,
    const float* __restrict__ w2, const float* __restrict__ b2,
    const float* __restrict__ w3, const float* __restrict__ b3,
    float* __restrict__ y,
    float* __restrict__ out_pos, float* __restrict__ out_batch, float* __restrict__ out_x,
    int* __restrict__ prog, int* __restrict__ yready)
{
    __shared__ float smem[24576];   // 96 KB
    const int tid = threadIdx.x;
    if (blockIdx.x < BG) {
        // ======== FPS producer (R3-exact structure, 8 waves x 8 pts/thread) ========
        const int b = blockIdx.x;
        const float* pg = pos + (size_t)b * NP * 3;
        for (int i = tid; i < NP * 3; i += 512) smem[i] = pg[i];
        __syncthreads();
        const int lane = tid & 63, wv = tid >> 6;
        float px[8], py[8], pz[8], mind[8];
        const int base = tid * 8;
        #pragma unroll
        for (int i = 0; i < 8; i++) {
            px[i] = smem[(base + i) * 3];
            py[i] = smem[(base + i) * 3 + 1];
            pz[i] = smem[(base + i) * 3 + 2];
            mind[i] = 1e30f;
        }
        float2* sl = (float2*)(smem + NP * 3);   // 2 x 8 double-buffered (V, idx) slots
        float cx = smem[0], cy = smem[1], cz = smem[2];
        if (tid == 0) {
            const size_t c3 = (size_t)b * MC * 3;
            __hip_atomic_store(&out_pos[c3 + 0], cx, __ATOMIC_RELAXED, __HIP_MEMORY_SCOPE_AGENT);
            __hip_atomic_store(&out_pos[c3 + 1], cy, __ATOMIC_RELAXED, __HIP_MEMORY_SCOPE_AGENT);
            __hip_atomic_store(&out_pos[c3 + 2], cz, __ATOMIC_RELAXED, __HIP_MEMORY_SCOPE_AGENT);
        }
        for (int m = 1; m < MC; m++) {
            float bv = -1.0f; int bi = base;
            #pragma unroll
            for (int i = 0; i < 8; i++) {
                float d = dist2(px[i], py[i], pz[i], cx, cy, cz);
                float nm = fminf(mind[i], d);
                mind[i] = nm;
                if (nm > bv) { bv = nm; bi = base + i; }  // strict > keeps first idx
            }
            float v = bv;
            v = dppmax<0x111>(v);  // row_shr:1
            v = dppmax<0x112>(v);  // row_shr:2
            v = dppmax<0x114>(v);  // row_shr:4
            v = dppmax<0x118>(v);  // row_shr:8
            v = dppmax<0x142>(v);  // row_bcast:15
            v = dppmax<0x143>(v);  // row_bcast:31
            const float V = __int_as_float(__builtin_amdgcn_readlane(__float_as_int(v), 63));
            unsigned long long mk = __ballot(bv == V);
            float2* sb = sl + (m & 1) * 8;
            if (lane == (int)(__ffsll((long long)mk) - 1))
                sb[wv] = make_float2(V, __int_as_float(bi));
            __syncthreads();   // also drains tid0's center-(m-1) stores (vmcnt)
            const float4* sq = (const float4*)sb;
            float4 q0 = sq[0], q1 = sq[1], q2 = sq[2], q3 = sq[3];
            float Vg = q0.x; int ig = __float_as_int(q0.y);
            if (q0.z > Vg) { Vg = q0.z; ig = __float_as_int(q0.w); }
            if (q1.x > Vg) { Vg = q1.x; ig = __float_as_int(q1.y); }
            if (q1.z > Vg) { Vg = q1.z; ig = __float_as_int(q1.w); }
            if (q2.x > Vg) { Vg = q2.x; ig = __float_as_int(q2.y); }
            if (q2.z > Vg) { Vg = q2.z; ig = __float_as_int(q2.w); }
            if (q3.x > Vg) { Vg = q3.x; ig = __float_as_int(q3.y); }
            if (q3.z > Vg) { Vg = q3.z; ig = __float_as_int(q3.w); }
            cx = smem[ig * 3]; cy = smem[ig * 3 + 1]; cz = smem[ig * 3 + 2];
            if (tid == 0) {
                const size_t c3 = (size_t)(b * MC + m) * 3;
                __hip_atomic_store(&out_pos[c3 + 0], cx, __ATOMIC_RELAXED, __HIP_MEMORY_SCOPE_AGENT);
                __hip_atomic_store(&out_pos[c3 + 1], cy, __ATOMIC_RELAXED, __HIP_MEMORY_SCOPE_AGENT);
                __hip_atomic_store(&out_pos[c3 + 2], cz, __ATOMIC_RELAXED, __HIP_MEMORY_SCOPE_AGENT);
                // centers 0..m-1 are drained (previous barrier waited vmcnt(0))
                __hip_atomic_store(&prog[b * 16], m, __ATOMIC_RELAXED, __HIP_MEMORY_SCOPE_AGENT);
            }
        }
        __syncthreads();   // drain last center's stores
        if (tid == 0)
            __hip_atomic_store(&prog[b * 16], MC, __ATOMIC_RELEASE, __HIP_MEMORY_SCOPE_AGENT);
        for (int i = tid; i < MC; i += 512) out_batch[b * MC + i] = (float)b;
    } else {
        // ======== Consumer block ========
        const int w = blockIdx.x - BG;        // 0..247
        const int g = w & 7;                  // graph
        const int sub = w >> 3;               // 0..30
        const int lane = tid & 63, ww = tid >> 6;
        const int waveid = sub * 8 + ww;      // 0..247 within graph
        // ---- phase 1: y = x @ W1x + b1 for this block's chunk of graph g ----
        float* wsm = smem;                    // [0, 4096): W1 x-part
        for (int i = tid; i < 4096; i += 512) wsm[i] = w1[i];
        const float b1v = b1[lane];
        __syncthreads();
        const int p0 = sub * 133;
        const int p1 = (p0 + 133 < NP) ? p0 + 133 : NP;
        const float* xg = x + (size_t)g * NP * 64;
        float* yg_w = y + (size_t)g * NP * 64;
        for (int p = p0 + ww; p < p1; p += 8) {
            float xrow = xg[(size_t)p * 64 + lane];
            float acc = b1v;
            #pragma unroll
            for (int f = 0; f < 64; f++) {
                float xf = __shfl(xrow, f, 64);
                acc = fmaf(xf, wsm[f * 64 + lane], acc);
            }
            yg_w[(size_t)p * 64 + lane] = acc;
        }
        __syncthreads();                      // drain this block's y stores
        if (tid == 0)
            __hip_atomic_fetch_add(&yready[g * 16], 1, __ATOMIC_RELEASE, __HIP_MEMORY_SCOPE_AGENT);
        // ---- phase 2: preload weights into registers (overlaps the wait) ----
        float w2c[64], w3a[64], w3b[64];
        #pragma unroll
        for (int f = 0; f < 64; f++) {
            w2c[f] = w2[f * 64 + lane];
            w3a[f] = w3[f * 128 + lane];
            w3b[f] = w3[f * 128 + 64 + lane];
        }
        const float b2v = b2[lane], b3av = b3[lane], b3bv = b3[lane + 64];
        const float wp0 = w1[64 * 64 + lane], wp1 = w1[65 * 64 + lane], wp2 = w1[66 * 64 + lane];
        while (__hip_atomic_load(&yready[g * 16], __ATOMIC_RELAXED, __HIP_MEMORY_SCOPE_AGENT) < 31)
            __builtin_amdgcn_s_sleep(16);
        {
            int yr = __hip_atomic_load(&yready[g * 16], __ATOMIC_ACQUIRE, __HIP_MEMORY_SCOPE_AGENT);
            asm volatile("" :: "v"(yr));      // keep the acquire load alive
        }
        float2* cand = (float2*)(smem + 4096) + ww * CAND;   // floats [4096, 11776)
        int* nlist = (int*)(smem + 11776) + ww * 64;         // floats [11776, 12288)
        float* st1 = smem + 12288 + ww * 136;                // floats [12288, 13376)
        float* st2 = st1 + 68;
        const float* pg = pos + (size_t)g * NP * 3;
        const float* yg = y + (size_t)g * NP * 64;
        for (int m = waveid; m < MC; m += NWK) {
            int cur;
            while ((cur = __hip_atomic_load(&prog[g * 16], __ATOMIC_RELAXED, __HIP_MEMORY_SCOPE_AGENT)) <= m) {
                if (m - cur > 16) __builtin_amdgcn_s_sleep(64);
                else              __builtin_amdgcn_s_sleep(8);
            }
            const int ci = g * MC + m;
            const size_t c3 = (size_t)ci * 3;
            const float cx = __hip_atomic_load(&out_pos[c3 + 0], __ATOMIC_RELAXED, __HIP_MEMORY_SCOPE_AGENT);
            const float cy = __hip_atomic_load(&out_pos[c3 + 1], __ATOMIC_RELAXED, __HIP_MEMORY_SCOPE_AGENT);
            const float cz = __hip_atomic_load(&out_pos[c3 + 2], __ATOMIC_RELAXED, __HIP_MEMORY_SCOPE_AGENT);
            int cnt = 0;
            for (int c = 0; c < 64; c++) {
                const int p = c * 64 + lane;
                float ppx = pg[p * 3], ppy = pg[p * 3 + 1], ppz = pg[p * 3 + 2];
                float d2 = dist2(ppx, ppy, ppz, cx, cy, cz);
                bool inr = d2 <= 0.25f;
                unsigned long long mk = __ballot(inr);
                int pre = __popcll(mk & ((1ull << lane) - 1ull));
                int wp = cnt + pre;
                if (inr && wp < CAND) cand[wp] = make_float2(d2, __int_as_float(p));
                cnt += __popcll(mk);
            }
            if (cnt > CAND) cnt = CAND;
            int kc;
            if (cnt <= KN) {
                kc = cnt;
                if (lane < cnt) nlist[lane] = __float_as_int(cand[lane].y);
            } else {
                kc = KN;
                for (int basej = 0; basej < cnt; basej += 64) {
                    int jj = basej + lane;
                    float dj = 3.4e38f; int ij = 0x7fffffff;
                    bool act = jj < cnt;
                    if (act) { float2 e = cand[jj]; dj = e.x; ij = __float_as_int(e.y); }
                    int rank = 0;
                    for (int l = 0; l < cnt; l++) {
                        float2 e = cand[l];
                        float dl = e.x; int il = __float_as_int(e.y);
                        if (dl < dj || (dl == dj && il < ij)) rank++;
                    }
                    if (act && rank < KN) nlist[rank] = ij;
                }
            }
            float mA = -3.4e38f, mB = -3.4e38f;
            for (int k = 0; k < kc; k++) {
                const int j = nlist[k];
                const float yv = yg[(size_t)j * 64 + lane];
                const float jx = pg[j * 3], jy = pg[j * 3 + 1], jz = pg[j * 3 + 2];
                float rx = jx - cx, ry = jy - cy, rz = jz - cz;
                float h1 = fmaf(rx, wp0, yv);
                h1 = fmaf(ry, wp1, h1);
                h1 = fmaf(rz, wp2, h1);
                h1 = fmaxf(h1, 0.f);
                st1[lane] = h1;
                float a2a = b2v, a2b = 0.f;
                #pragma unroll
                for (int fc = 0; fc < 16; fc += 2) {
                    float4 hA = *(const float4*)&st1[fc * 4];
                    float4 hB = *(const float4*)&st1[fc * 4 + 4];
                    a2a = fmaf(hA.x, w2c[fc * 4], a2a);
                    a2a = fmaf(hA.y, w2c[fc * 4 + 1], a2a);
                    a2a = fmaf(hA.z, w2c[fc * 4 + 2], a2a);
                    a2a = fmaf(hA.w, w2c[fc * 4 + 3], a2a);
                    a2b = fmaf(hB.x, w2c[fc * 4 + 4], a2b);
                    a2b = fmaf(hB.y, w2c[fc * 4 + 5], a2b);
                    a2b = fmaf(hB.z, w2c[fc * 4 + 6], a2b);
                    a2b = fmaf(hB.w, w2c[fc * 4 + 7], a2b);
                }
                float h2 = fmaxf(a2a + a2b, 0.f);
                st2[lane] = h2;
                float a3 = b3av, a4 = b3bv;
                #pragma unroll
                for (int fc = 0; fc < 16; fc++) {
                    float4 h = *(const float4*)&st2[fc * 4];
                    a3 = fmaf(h.x, w3a[fc * 4], a3);
                    a3 = fmaf(h.y, w3a[fc * 4 + 1], a3);
                    a3 = fmaf(h.z, w3a[fc * 4 + 2], a3);
                    a3 = fmaf(h.w, w3a[fc * 4 + 3], a3);
                    a4 = fmaf(h.x, w3b[fc * 4], a4);
                    a4 = fmaf(h.y, w3b[fc * 4 + 1], a4);
                    a4 = fmaf(h.z, w3b[fc * 4 + 2], a4);
                    a4 = fmaf(h.w, w3b[fc * 4 + 3], a4);
                }
                mA = fmaxf(mA, a3);
                mB = fmaxf(mB, a4);
            }
            out_x[(size_t)ci * 128 + lane] = mA;
            out_x[(size_t)ci * 128 + 64 + lane] = mB;
        }
    }
}

extern "C" void kernel_launch(void* const* d_in, const int* in_sizes, int n_in,
                              void* d_out, int out_size, void* d_ws, size_t ws_size,
                              hipStream_t stream) {
    const float* x   = (const float*)d_in[0];
    const float* pos = (const float*)d_in[1];
    const float* w1  = (const float*)d_in[3];
    const float* b1  = (const float*)d_in[4];
    const float* w2  = (const float*)d_in[5];
    const float* b2  = (const float*)d_in[6];
    const float* w3  = (const float*)d_in[7];
    const float* b3  = (const float*)d_in[8];

    float* out_x     = (float*)d_out;                       // [B*M,128]
    float* out_pos   = out_x + (size_t)BG * MC * 128;       // [B*M,3]
    float* out_batch = out_pos + (size_t)BG * MC * 3;       // [B*M] (written as float)

    char* ws    = (char*)d_ws;
    float* y    = (float*)ws;                   // 8 MB: [B*N,64] = x@W1x + b1
    int* prog   = (int*)(ws + 8388608);         // 8 x 16 ints (64B stride per graph)
    int* yready = (int*)(ws + 8389120);         // 8 x 16 ints

    (void)hipMemsetAsync(prog, 0, 1024, stream);  // prog + yready
    hipLaunchKernelGGL(k_fused, dim3(256), dim3(512), 0, stream,
                       pos, x, w1, b1, w2, b2, w3, b3,
                       y, out_pos, out_batch, out_x, prog, yready);
}